// Round 7
// baseline (489.420 us; speedup 1.0000x reference)
//
#include <hip/hip_runtime.h>

#define NN 100000
#define EE 600000
#define HH 128
#define GG 1000
#define NPAD 100096   // 1564 * 64
#define NBLK2 1564

typedef __attribute__((ext_vector_type(8))) short bf16x8;
typedef __attribute__((ext_vector_type(4))) float f32x4;
typedef _Float16 f16;

__device__ inline short f2bf(float x){
    unsigned u = __float_as_uint(x);
    unsigned r = (u + 0x7FFFu + ((u >> 16) & 1u)) >> 16;
    return (short)r;
}
__device__ inline float bf2f(short h){
    unsigned u = ((unsigned)(unsigned short)h) << 16;
    return __uint_as_float(u);
}
__device__ inline float2 cvt2(unsigned u){
    f16 lo = ((const f16*)&u)[0];
    f16 hi = ((const f16*)&u)[1];
    return make_float2((float)lo, (float)hi);
}

// wave-wide dword load, uniform SGPR base + per-lane byte offset. asm volatile
// + "memory" pins issue order; the destination register is NOT valid until a
// counted vmcnt wait retires it. NEVER copy or read it before that wait.
#define GLD(dst, voff, sbase) \
    asm volatile("global_load_dword %0, %1, %2" \
                 : "=v"(dst) : "v"(voff), "s"(sbase) : "memory")

// counted vmem wait + full scheduler fence (rule #18)
#define WAITV(N) do { \
    asm volatile("s_waitcnt vmcnt(" #N ")" ::: "memory"); \
    __builtin_amdgcn_sched_barrier(0); \
} while (0)

// ---------------- CSR build ----------------
__global__ void k_hist(const int* __restrict__ dst, int* __restrict__ cnt){
    int e = blockIdx.x*256 + threadIdx.x;
    if (e < EE) atomicAdd(&cnt[dst[e]], 1);
}

__global__ void k_scan1(const int* __restrict__ cnt, int* __restrict__ excl,
                        int* __restrict__ bsums, int n){
    __shared__ int wsum[4];
    int t = threadIdx.x;
    int idx = blockIdx.x*1024 + t*4;
    int c[4];
#pragma unroll
    for (int i = 0; i < 4; i++) c[i] = (idx+i < n) ? cnt[idx+i] : 0;
    int s = c[0]+c[1]+c[2]+c[3];
    int lane = t & 63, w = t >> 6;
    int x = s;
#pragma unroll
    for (int off = 1; off < 64; off <<= 1){
        int y = __shfl_up(x, off);
        if (lane >= off) x += y;
    }
    if (lane == 63) wsum[w] = x;
    __syncthreads();
    int woff = 0;
    for (int i = 0; i < w; i++) woff += wsum[i];
    int run = woff + x - s;
#pragma unroll
    for (int i = 0; i < 4; i++){
        if (idx+i < n) excl[idx+i] = run;
        run += c[i];
    }
    if (t == 255) bsums[blockIdx.x] = woff + x;
}

__global__ void k_scan2(int* __restrict__ bsums, int nb){
    __shared__ int ws2[2];
    int t = threadIdx.x;
    int v = (t < nb) ? bsums[t] : 0;
    int lane = t & 63, w = t >> 6;
    int x = v;
#pragma unroll
    for (int off = 1; off < 64; off <<= 1){
        int y = __shfl_up(x, off);
        if (lane >= off) x += y;
    }
    if (lane == 63) ws2[w] = x;
    __syncthreads();
    int off0 = (w == 1) ? ws2[0] : 0;
    if (t < nb) bsums[t] = off0 + x - v;
}

__global__ void k_scan3(int* __restrict__ rp, const int* __restrict__ bsums,
                        int* __restrict__ fill, int n){
    int i = blockIdx.x*256 + threadIdx.x;
    if (i < n){
        int r = rp[i] + bsums[i >> 10];
        rp[i] = r;
        fill[i] = r;
    }
    if (i == 0) rp[n] = EE;
}

// place edges sorted by dst; pack (src<<4)|(dst&15) — dst&15 is the row
// within the owning wave's 16-row tile (tiles are 16-aligned).
__global__ void k_place(const int* __restrict__ src, const int* __restrict__ dst,
                        int* __restrict__ fill, int* __restrict__ spk){
    int e = blockIdx.x*256 + threadIdx.x;
    if (e < EE){
        int d = dst[e];
        int p = atomicAdd(&fill[d], 1);
        spk[p] = (src[e] << 4) | (d & 15);
    }
}

// ---------------- init: zero fill + graph rowptr + W pre-swizzle (merged) ----
__global__ void k_init(const int* __restrict__ batch, int* __restrict__ fill,
                       int* __restrict__ rp_g,
                       const float* __restrict__ W2_0, const float* __restrict__ W1s,
                       const float* __restrict__ W2s, short* __restrict__ Wp){
    int tid = blockIdx.x*256 + threadIdx.x;
    if (tid < NN){
        fill[tid] = 0;
        int b = batch[tid];
        if (tid == 0){
            for (int g = 0; g <= b; g++) rp_g[g] = 0;
        } else {
            int p = batch[tid-1];
            for (int g = p+1; g <= b; g++) rp_g[g] = tid;
        }
        if (tid == NN-1){
            for (int g = b+1; g <= GG; g++) rp_g[g] = NN;
        }
    }
    if (tid < 9*16384){
        int m = tid >> 14;
        int r = tid & 16383;
        int j = r & 7, l = (r >> 3) & 63, ctkc = r >> 9;
        int ct = ctkc & 7, kc = ctkc >> 3;
        int k = kc*32 + ((l >> 4) << 3) + j;
        int n = (ct << 4) + (l & 15);
        const float* W = (m == 0) ? W2_0
                       : (m <= 4) ? (W1s + (size_t)(m-1)*HH*HH)
                                  : (W2s + (size_t)(m-5)*HH*HH);
        float w = W[k*HH + n];
        short hi = f2bf(w);
        short lo = f2bf(w - bf2f(hi));
        short* base = Wp + (size_t)m*32768;
        base[r] = hi;
        base[16384 + r] = lo;
    }
}

// ---------------- layer 0 aggregation (in=3) ----------------
__global__ void k_agg3(const float* __restrict__ x, const int* __restrict__ rp,
                       const int* __restrict__ spk, float* __restrict__ y){
    int i = blockIdx.x*256 + threadIdx.x;
    if (i >= NN) return;
    float a0 = x[3*i], a1 = x[3*i+1], a2 = x[3*i+2];
    int b = rp[i], e = rp[i+1];
    for (int k = b; k < e; k++){
        int s = spk[k] >> 4;
        a0 += x[3*s]; a1 += x[3*s+1]; a2 += x[3*s+2];
    }
    y[3*i] = a0; y[3*i+1] = a1; y[3*i+2] = a2;
}

// ============ per-wave LDS layouts (no cross-wave sharing, NO barriers) ======

__device__ inline void wave_gemm(const short* __restrict__ sAh,
                                 const short* __restrict__ sAl,
                                 const short* __restrict__ Wp,
                                 int n, int q, f32x4* acc){
    const short* Wh = Wp;
    const short* Wl = Wp + 16384;
    const int l = (q << 4) | n;
#pragma unroll
    for (int ct = 0; ct < 8; ct++) acc[ct] = (f32x4){0.f,0.f,0.f,0.f};
#pragma unroll
    for (int kc = 0; kc < 4; kc++){
        int c = (q << 4) | (n & 8) | ((n & 7) ^ ((q & 1) << 2) ^ kc);
        int pos = kc*512 + c*8;
        bf16x8 ah = *(const bf16x8*)&sAh[pos];
        bf16x8 al = *(const bf16x8*)&sAl[pos];
        const short* ph = Wh + (size_t)(kc*8)*512 + l*8;
        const short* pl = Wl + (size_t)(kc*8)*512 + l*8;
#pragma unroll
        for (int ct = 0; ct < 8; ct++){
            bf16x8 bh = *(const bf16x8*)(ph + ct*512);
            bf16x8 bl = *(const bf16x8*)(pl + ct*512);
            acc[ct] = __builtin_amdgcn_mfma_f32_16x16x32_bf16(ah, bh, acc[ct], 0, 0, 0);
            acc[ct] = __builtin_amdgcn_mfma_f32_16x16x32_bf16(al, bh, acc[ct], 0, 0, 0);
            acc[ct] = __builtin_amdgcn_mfma_f32_16x16x32_bf16(ah, bl, acc[ct], 0, 0, 0);
        }
    }
}

// ---------------- layer 0 fused: mlp0 + GEMM(W2_0); fp16 output ----
__global__ __launch_bounds__(256, 4)
void k_layer0(const float* __restrict__ y0, const short* __restrict__ Wp,
              const float* __restrict__ W1, const float* __restrict__ b1,
              const float* __restrict__ g, const float* __restrict__ be,
              const float* __restrict__ m, const float* __restrict__ v,
              const float* __restrict__ b2, f16* __restrict__ out){
    __shared__ __align__(16) char smem[32768];
    const int t = threadIdx.x;
    const int w = t >> 6, l = t & 63;
    short* sAh = (short*)(smem + w*8192);
    short* sAl = (short*)(smem + w*8192 + 4096);
    const int R0 = blockIdx.x*64 + w*16;

    {
        int hw = l >> 5, ln = l & 31;
        int c4 = ln << 2;
        int kc1 = ln >> 3, q1 = (ln >> 1) & 3, j1 = (ln & 1) << 2;
        float Wc[3][4], Ac[4], Bc[4];
#pragma unroll
        for (int i = 0; i < 4; i++){
            int c = c4 + i;
            float rs = rsqrtf(v[c] + 1e-5f);
            float sc = g[c]*rs;
            Ac[i] = sc;
            Bc[i] = sc*(b1[c] - m[c]) + be[c];
            Wc[0][i] = W1[c]; Wc[1][i] = W1[HH + c]; Wc[2][i] = W1[2*HH + c];
        }
        float ya[8], yb[8], yc[8];
#pragma unroll
        for (int it = 0; it < 8; it++){
            int node = R0 + hw + (it << 1);
            ya[it] = y0[3*node]; yb[it] = y0[3*node+1]; yc[it] = y0[3*node+2];
        }
#pragma unroll
        for (int it = 0; it < 8; it++){
            int mm = hw + (it << 1);
            float xs[4];
#pragma unroll
            for (int i = 0; i < 4; i++){
                float raw = ya[it]*Wc[0][i] + yb[it]*Wc[1][i] + yc[it]*Wc[2][i];
                xs[i] = fmaxf(fmaf(raw, Ac[i], Bc[i]), 0.f);
            }
            int c = (q1 << 4) | (mm & 8) | ((mm & 7) ^ ((q1 & 1) << 2) ^ kc1);
            int pos = kc1*512 + c*8 + j1;
            unsigned hp[2], lp[2];
#pragma unroll
            for (int i = 0; i < 2; i++){
                unsigned u0 = __float_as_uint(xs[2*i]);
                unsigned u1 = __float_as_uint(xs[2*i+1]);
                float r0 = xs[2*i]   - __uint_as_float(u0 & 0xFFFF0000u);
                float r1 = xs[2*i+1] - __uint_as_float(u1 & 0xFFFF0000u);
                hp[i] = (u0 >> 16) | (u1 & 0xFFFF0000u);
                lp[i] = (__float_as_uint(r0) >> 16) | (__float_as_uint(r1) & 0xFFFF0000u);
            }
            *(uint2*)&sAh[pos] = make_uint2(hp[0], hp[1]);
            *(uint2*)&sAl[pos] = make_uint2(lp[0], lp[1]);
        }
    }
    __asm__ volatile("" ::: "memory");

    const int n = l & 15, q = l >> 4;
    f32x4 acc[8];
    wave_gemm(sAh, sAl, Wp, n, q, acc);
#pragma unroll
    for (int ct = 0; ct < 8; ct++){
        int j = (ct << 4) + n;
        float shv = b2[j];
#pragma unroll
        for (int r = 0; r < 4; r++){
            int row = R0 + q*4 + r;
            out[(size_t)row*HH + j] = (f16)fmaxf(acc[ct][r] + shv, 0.f);
        }
    }
}

// ================= full GIN layer: fp16 h, asm-pipelined gather, f32-LDS GEMMs
// LDS tile per wave: 16 rows x 128 f32 (8 KB), XOR-swizzled:
//   idx(row,k) = row*128 + (k ^ ((row&7)<<2))   [== byte ^ ((row&7)<<4)]
__device__ __forceinline__ int sidx(int r, int k){
    return r*128 + (k ^ ((r & 7) << 2));
}

// GEMM with A read from f32 LDS tile, split to bf16 hi/lo on the fly.
__device__ __forceinline__ void wave_gemm_f32(const float* __restrict__ sF,
                                              const short* __restrict__ Wp,
                                              int l, f32x4* acc){
    const short* Wh = Wp;
    const short* Wl = Wp + 16384;
    const int rw = l & 15, q = l >> 4;
    const int v7 = (rw & 7) << 2;
    const int rbase = rw << 7;
#pragma unroll
    for (int ct = 0; ct < 8; ct++) acc[ct] = (f32x4){0.f,0.f,0.f,0.f};
#pragma unroll
    for (int kc = 0; kc < 4; kc++){
        int k0 = kc*32 + (q << 3);
        float4 fa = *(const float4*)&sF[rbase + ((k0    ) ^ v7)];
        float4 fb = *(const float4*)&sF[rbase + ((k0 + 4) ^ v7)];
        float xs[8] = {fa.x,fa.y,fa.z,fa.w,fb.x,fb.y,fb.z,fb.w};
        bf16x8 ah, al;
#pragma unroll
        for (int i = 0; i < 8; i++){
            unsigned u = __float_as_uint(xs[i]);
            ah[i] = (short)(u >> 16);
            float rv = xs[i] - __uint_as_float(u & 0xFFFF0000u);
            al[i] = (short)(__float_as_uint(rv) >> 16);
        }
        const short* ph = Wh + (size_t)(kc*8)*512 + l*8;
        const short* pl = Wl + (size_t)(kc*8)*512 + l*8;
#pragma unroll
        for (int ct = 0; ct < 8; ct++){
            bf16x8 bh = *(const bf16x8*)(ph + ct*512);
            bf16x8 bl = *(const bf16x8*)(pl + ct*512);
            acc[ct] = __builtin_amdgcn_mfma_f32_16x16x32_bf16(ah, bh, acc[ct], 0, 0, 0);
            acc[ct] = __builtin_amdgcn_mfma_f32_16x16x32_bf16(al, bh, acc[ct], 0, 0, 0);
            acc[ct] = __builtin_amdgcn_mfma_f32_16x16x32_bf16(ah, bl, acc[ct], 0, 0, 0);
        }
    }
}

// per-edge accumulate with wave-uniform row-switch bookkeeping
#define PROC_EDGE(uval, sival) do { \
    int lr_ = (sival) & 15; \
    if (lr_ != cur){ \
        if (cur >= 0){ \
            int off_ = cur*128 + ((2*l) ^ ((cur & 7) << 2)); \
            *(float2*)&sF[off_] = make_float2(acc0, acc1); \
        } \
        cur = lr_; \
        int off_ = lr_*128 + ((2*l) ^ ((lr_ & 7) << 2)); \
        float2 sv_ = *(const float2*)&sF[off_]; \
        acc0 = sv_.x; acc1 = sv_.y; \
    } \
    float2 fv_ = cvt2(uval); \
    acc0 += fv_.x; acc1 += fv_.y; \
} while (0)

// issue a full 32-edge chunk's data loads (idx register J must be LANDED)
#define ISSUE_CHUNK(U, J) do { \
    _Pragma("unroll") \
    for (int j_ = 0; j_ < 32; j_++){ \
        int sj_ = __builtin_amdgcn_readlane((J), j_) >> 4; \
        GLD(U[j_], voff, A2 + (size_t)sj_*64); \
    } \
} while (0)

// issue the partial tail chunk (remT < 32 edges; J landed)
#define ISSUE_TAIL(U, J) do { \
    _Pragma("unroll") \
    for (int j_ = 0; j_ < 32; j_++){ \
        if (j_ < remT){ \
            int sj_ = __builtin_amdgcn_readlane((J), j_) >> 4; \
            GLD(U[j_], voff, A2 + (size_t)sj_*64); \
        } \
    } \
} while (0)

// process a full chunk (U data and J idx both LANDED)
#define PROC_CHUNK(U, J) do { \
    _Pragma("unroll") \
    for (int j_ = 0; j_ < 32; j_++){ \
        int si_ = __builtin_amdgcn_readlane((J), j_); \
        PROC_EDGE(U[j_], si_); \
    } \
} while (0)

#define PROC_TAIL(U, J) do { \
    _Pragma("unroll") \
    for (int j_ = 0; j_ < 32; j_++){ \
        if (j_ < remT){ \
            int si_ = __builtin_amdgcn_readlane((J), j_); \
            PROC_EDGE(U[j_], si_); \
        } \
    } \
} while (0)

__global__ __launch_bounds__(256, 3)
void k_layer(const f16* __restrict__ A, const int* __restrict__ rp,
             const int* __restrict__ spk,
             const short* __restrict__ Wp1, const short* __restrict__ Wp2,
             const float* __restrict__ b1, const float* __restrict__ g,
             const float* __restrict__ be, const float* __restrict__ m,
             const float* __restrict__ v, const float* __restrict__ b2,
             f16* __restrict__ out){
    __shared__ __align__(16) float smemf[8192];   // 32 KB, 8 KB per wave
    const int t = threadIdx.x;
    const int w = t >> 6, l = t & 63;
    float* sF = smemf + w*2048;
    const int r0w = blockIdx.x*64 + w*16;
    const unsigned* A2 = (const unsigned*)A;      // 64 dwords per row

    // ---- phase 1a: self rows -> LDS (swizzled), dwordx2 per lane ----
    {
        int half = l >> 5, lm = l & 31;
        int k0 = lm << 2;                          // float col base (4 per lane)
#pragma unroll
        for (int i = 0; i < 8; i++){
            int r = (i << 1) + half;
            uint2 u = *(const uint2*)&A2[(size_t)(r0w + r)*64 + (lm << 1)];
            float2 f0 = cvt2(u.x), f1 = cvt2(u.y);
            int base = r*128 + (k0 ^ ((r & 7) << 2));   // 4-aligned after xor
            *(float4*)&sF[base] = make_float4(f0.x, f0.y, f1.x, f1.y);
        }
    }

    // ---- phase 1b: 4-chunk-unrolled asm pipeline, ZERO register copies ----
    // J0..J3 statically bound to chunk k mod 4; U0/U1 ping-pong by parity.
    // Invariant at loop top: in-flight (issue order) = [U0=data(c) x32,
    // J2=idx(c+2), J3=idx(c+3)] = 34; J0=idx(c), J1=idx(c+1) landed.
    {
        int rlo = r0w < NN ? r0w : NN;
        int rhi = (r0w + 16) < NN ? (r0w + 16) : NN;   // NN%16==0: no straddle
        int elo = __builtin_amdgcn_readfirstlane(rp[rlo]);
        int ehi = __builtin_amdgcn_readfirstlane(rp[rhi]);
        int nE  = ehi - elo;
        int nfull = nE >> 5;
        int remT  = nE & 31;
        int voff = l << 2;            // byte offset into a 256B fp16 row
        int vio  = (l & 31) << 2;     // byte offset for 32-int idx loads
        float acc0 = 0.f, acc1 = 0.f;
        int cur = -1;
        unsigned U0[32], U1[32];
        int J0, J1, J2, J3;
        const int* sp = spk + elo;    // idx over-reads stay in 128-int pad

        if (nfull == 0){
            if (remT > 0){
                GLD(J0, vio, sp);
                WAITV(0);
                ISSUE_TAIL(U0, J0);
                WAITV(0);
                PROC_TAIL(U0, J0);
            }
        } else {
            GLD(J0, vio, sp);
            GLD(J1, vio, sp + 32);
            WAITV(0);                       // J0, J1 landed
            ISSUE_CHUNK(U0, J0);            // [U0x32]
            GLD(J2, vio, sp + 64);          // [U0,J2]
            GLD(J3, vio, sp + 96);          // [U0,J2,J3] = 34  (invariant)

            int c = 0;
            while (c + 4 < nfull){
                ISSUE_CHUNK(U1, J1);            // [U0,J2,J3,U1] 66
                WAITV(34);                      // U0 landed; [J2,J3,U1] 34
                PROC_CHUNK(U0, J0);
                WAITV(33);                      // J2 landed; [J3,U1] 33
                GLD(J0, vio, sp + c*32 + 128);  // idx(c+4); [J3,U1,J0] 34
                ISSUE_CHUNK(U0, J2);            // data(c+2); [J3,U1,J0,U0'] 66
                WAITV(33);                      // J3,U1 landed; [J0,U0'] 33
                PROC_CHUNK(U1, J1);
                GLD(J1, vio, sp + c*32 + 160);  // idx(c+5); [J0,U0',J1] 34
                ISSUE_CHUNK(U1, J3);            // data(c+3); [J0,U0',J1,U1'] 66
                WAITV(33);                      // J0,U0' landed; [J1,U1'] 33
                PROC_CHUNK(U0, J2);
                ISSUE_CHUNK(U0, J0);            // data(c+4); [J1,U1',U0''] 65
                GLD(J2, vio, sp + c*32 + 192);  // idx(c+6); [J1,U1',U0'',J2] 66
                WAITV(33);                      // J1,U1' landed; [U0'',J2] 33
                PROC_CHUNK(U1, J3);
                GLD(J3, vio, sp + c*32 + 224);  // idx(c+7); [U0'',J2,J3] 34 ✓
                c += 4;
            }

            int rem = nfull - c;                // in {1,2,3,4}
            if (rem == 1){
                // tail idx = idx(c+1) = J1 (landed)
                ISSUE_TAIL(U1, J1);             // [U0,J2,J3,tail]
                WAITV(0);
                PROC_CHUNK(U0, J0);
                PROC_TAIL(U1, J1);
            } else if (rem == 2){
                ISSUE_CHUNK(U1, J1);            // 66
                WAITV(34);                      // U0 landed
                PROC_CHUNK(U0, J0);
                WAITV(33);                      // J2 landed (tail idx)
                ISSUE_TAIL(U0, J2);             // [J3,U1,tail]
                WAITV(0);
                PROC_CHUNK(U1, J1);
                PROC_TAIL(U0, J2);
            } else if (rem == 3){
                ISSUE_CHUNK(U1, J1);            // 66
                WAITV(34);                      // U0 landed
                PROC_CHUNK(U0, J0);
                WAITV(33);                      // J2 landed; [J3,U1] 33
                ISSUE_CHUNK(U0, J2);            // data(c+2); 65
                WAITV(32);                      // J3,U1 landed; [U0'] 32
                PROC_CHUNK(U1, J1);
                ISSUE_TAIL(U1, J3);             // tail via J3; [U0',tail]
                WAITV(0);
                PROC_CHUNK(U0, J2);
                PROC_TAIL(U1, J3);
            } else { // rem == 4; tail idx = idx(c+4), not yet loaded
                ISSUE_CHUNK(U1, J1);            // 66
                WAITV(34);                      // U0 landed
                PROC_CHUNK(U0, J0);
                WAITV(33);                      // J2 landed; [J3,U1] 33
                GLD(J0, vio, sp + c*32 + 128);  // tail idx; [J3,U1,J0] 34
                ISSUE_CHUNK(U0, J2);            // data(c+2); [J3,U1,J0,U0'] 66
                WAITV(33);                      // J3,U1 landed; [J0,U0'] 33
                PROC_CHUNK(U1, J1);
                ISSUE_CHUNK(U1, J3);            // data(c+3); [J0,U0',U1'] 65
                WAITV(32);                      // J0,U0' landed; [U1'] 32
                PROC_CHUNK(U0, J2);
                ISSUE_TAIL(U0, J0);             // tail via J0; [U1',tail]
                WAITV(0);
                PROC_CHUNK(U1, J3);
                PROC_TAIL(U0, J0);
            }
        }
        if (cur >= 0){
            int off = cur*128 + ((2*l) ^ ((cur & 7) << 2));
            *(float2*)&sF[off] = make_float2(acc0, acc1);
        }
        WAITV(0);
    }
    __asm__ volatile("" ::: "memory");

    const int n = l & 15, q = l >> 4;

    // ---- phase 2: GEMM1 (A from f32 LDS); BN/ReLU epilogue -> back to LDS ----
    f32x4 acc[8];
    wave_gemm_f32(sF, Wp1, l, acc);
    __asm__ volatile("" ::: "memory");
#pragma unroll
    for (int ct = 0; ct < 8; ct++){
        int j = (ct << 4) + n;
        float rr = rsqrtf(v[j] + 1e-5f);
        float scv = g[j]*rr;
        float shv = be[j] + scv*(b1[j] - m[j]);
#pragma unroll
        for (int r = 0; r < 4; r++){
            int row = (q << 2) + r;
            float vv = fmaxf(fmaf(acc[ct][r], scv, shv), 0.f);
            sF[sidx(row, j)] = vv;
        }
    }
    __asm__ volatile("" ::: "memory");

    // ---- phase 3: GEMM2 + bias/ReLU -> global (fp16) ----
    wave_gemm_f32(sF, Wp2, l, acc);
#pragma unroll
    for (int ct = 0; ct < 8; ct++){
        int j = (ct << 4) + n;
        float shv = b2[j];
#pragma unroll
        for (int r = 0; r < 4; r++){
            int row = r0w + (q << 2) + r;
            out[(size_t)row*HH + j] = (f16)fmaxf(acc[ct][r] + shv, 0.f);
        }
    }
}

// ---------------- pooling + classifier: block per graph, no atomics ---------
__global__ void k_pool2(const f16* __restrict__ h, const float* __restrict__ Wc,
                        const float* __restrict__ bc, const int* __restrict__ rp_g,
                        float* __restrict__ out){
    __shared__ float ws[4];
    int g = blockIdx.x, t = threadIdx.x;
    const unsigned* h2 = (const unsigned*)h;      // 64 dwords per row
    long beg = (long)rp_g[g]*64, end = (long)rp_g[g+1]*64;
    float s = 0.f;
    for (long i = beg + t; i < end; i += 256){
        unsigned u = h2[i];
        int p = (int)(i & 63);
        float2 fv = cvt2(u);
        s += fv.x*Wc[2*p] + fv.y*Wc[2*p+1];
    }
    int lane = t & 63, w = t >> 6;
#pragma unroll
    for (int off = 32; off > 0; off >>= 1) s += __shfl_down(s, off);
    if (lane == 0) ws[w] = s;
    __syncthreads();
    if (t == 0) out[g] = bc[0] + ws[0] + ws[1] + ws[2] + ws[3];
}

extern "C" void kernel_launch(void* const* d_in, const int* in_sizes, int n_in,
                              void* d_out, int out_size, void* d_ws, size_t ws_size,
                              hipStream_t stream){
    const float* x     = (const float*)d_in[0];
    const int*   ei    = (const int*)d_in[1];
    const int*   batch = (const int*)d_in[2];
    const float* W1_0  = (const float*)d_in[3];
    const float* b1_0  = (const float*)d_in[4];
    const float* g_0   = (const float*)d_in[5];
    const float* be_0  = (const float*)d_in[6];
    const float* m_0   = (const float*)d_in[7];
    const float* v_0   = (const float*)d_in[8];
    const float* W2_0  = (const float*)d_in[9];
    const float* b2_0  = (const float*)d_in[10];
    const float* W1s   = (const float*)d_in[11];
    const float* b1s   = (const float*)d_in[12];
    const float* gs    = (const float*)d_in[13];
    const float* bes   = (const float*)d_in[14];
    const float* ms    = (const float*)d_in[15];
    const float* vs    = (const float*)d_in[16];
    const float* W2s   = (const float*)d_in[17];
    const float* b2s   = (const float*)d_in[18];
    const float* Wc    = (const float*)d_in[19];
    const float* bc    = (const float*)d_in[20];

    f16* H0 = (f16*)d_ws;                         // NPAD*HH halfs
    f16* H1 = H0 + (size_t)NPAD*HH;
    int* rp    = (int*)(H1 + (size_t)NPAD*HH);
    int* fill  = rp + (NN + 1);
    int* spk   = fill + NN;
    int* bsums = spk + EE + 128;                  // spk padded by 128 ints
    int* rp_g  = bsums + 128;
    size_t off = (size_t)((char*)(rp_g + (GG + 1)) - (char*)d_ws);
    off = (off + 15) & ~(size_t)15;
    short* Wp = (short*)((char*)d_ws + off);
    float* Y  = (float*)H1;                       // f32 agg3 output (aliases H1)

    const int* src = ei;
    const int* dst = ei + EE;

    // --- init (zero fill + rp_g bounds + weight pre-swizzle, one kernel) ---
    k_init<<<(9*16384+255)/256, 256, 0, stream>>>(batch, fill, rp_g,
                                                  W2_0, W1s, W2s, Wp);

    // --- CSR build ---
    k_hist<<<(EE+255)/256, 256, 0, stream>>>(dst, fill);
    k_scan1<<<98, 256, 0, stream>>>(fill, rp, bsums, NN);
    k_scan2<<<1, 128, 0, stream>>>(bsums, 98);
    k_scan3<<<(NN+255)/256, 256, 0, stream>>>(rp, bsums, fill, NN);
    k_place<<<(EE+255)/256, 256, 0, stream>>>(src, dst, fill, spk);

    // --- layer 0: agg3 (f32, into Y=H1 alias) -> fused mlp0+GEMM -> H0 fp16 ---
    k_agg3<<<(NN+255)/256, 256, 0, stream>>>(x, rp, spk, Y);
    k_layer0<<<NBLK2, 256, 0, stream>>>(Y, Wp, W1_0, b1_0, g_0, be_0, m_0, v_0,
                                        b2_0, H0);

    // --- layers 1..4: one fused barrier-free kernel per layer ---
    f16* cur = H0; f16* oth = H1;
    for (int l = 0; l < 4; l++){
        k_layer<<<NBLK2, 256, 0, stream>>>(cur, rp, spk,
                                           Wp + (size_t)(1+l)*32768,
                                           Wp + (size_t)(5+l)*32768,
                                           b1s + l*HH, gs + l*HH, bes + l*HH,
                                           ms + l*HH, vs + l*HH, b2s + l*HH,
                                           oth);
        f16* tmp = cur; cur = oth; oth = tmp;
    }

    // --- pooling + classifier (no atomics) ---
    k_pool2<<<GG, 256, 0, stream>>>(cur, Wc, bc, rp_g, (float*)d_out);
}

// Round 9
// 455.062 us; speedup vs baseline: 1.0755x; 1.0755x over previous
//
#include <hip/hip_runtime.h>

#define NN 100000
#define EE 600000
#define HH 128
#define GG 1000
#define NPAD 100096   // 1564 * 64
#define NBLK2 1564    // k_layer0: 64 rows/block
#define NBLKL 3128    // k_layer: 32 rows/block (2 waves x 16)

typedef __attribute__((ext_vector_type(8))) short bf16x8;
typedef __attribute__((ext_vector_type(4))) float f32x4;
typedef _Float16 f16;

__device__ inline short f2bf(float x){
    unsigned u = __float_as_uint(x);
    unsigned r = (u + 0x7FFFu + ((u >> 16) & 1u)) >> 16;
    return (short)r;
}
__device__ inline float bf2f(short h){
    unsigned u = ((unsigned)(unsigned short)h) << 16;
    return __uint_as_float(u);
}
__device__ inline float2 cvt2(unsigned u){
    f16 lo = ((const f16*)&u)[0];
    f16 hi = ((const f16*)&u)[1];
    return make_float2((float)lo, (float)hi);
}

// ---------------- CSR build ----------------
__global__ void k_hist(const int* __restrict__ dst, int* __restrict__ cnt){
    int e = blockIdx.x*256 + threadIdx.x;
    if (e < EE) atomicAdd(&cnt[dst[e]], 1);
}

__global__ void k_scan1(const int* __restrict__ cnt, int* __restrict__ excl,
                        int* __restrict__ bsums, int n){
    __shared__ int wsum[4];
    int t = threadIdx.x;
    int idx = blockIdx.x*1024 + t*4;
    int c[4];
#pragma unroll
    for (int i = 0; i < 4; i++) c[i] = (idx+i < n) ? cnt[idx+i] : 0;
    int s = c[0]+c[1]+c[2]+c[3];
    int lane = t & 63, w = t >> 6;
    int x = s;
#pragma unroll
    for (int off = 1; off < 64; off <<= 1){
        int y = __shfl_up(x, off);
        if (lane >= off) x += y;
    }
    if (lane == 63) wsum[w] = x;
    __syncthreads();
    int woff = 0;
    for (int i = 0; i < w; i++) woff += wsum[i];
    int run = woff + x - s;
#pragma unroll
    for (int i = 0; i < 4; i++){
        if (idx+i < n) excl[idx+i] = run;
        run += c[i];
    }
    if (t == 255) bsums[blockIdx.x] = woff + x;
}

__global__ void k_scan2(int* __restrict__ bsums, int nb){
    __shared__ int ws2[2];
    int t = threadIdx.x;
    int v = (t < nb) ? bsums[t] : 0;
    int lane = t & 63, w = t >> 6;
    int x = v;
#pragma unroll
    for (int off = 1; off < 64; off <<= 1){
        int y = __shfl_up(x, off);
        if (lane >= off) x += y;
    }
    if (lane == 63) ws2[w] = x;
    __syncthreads();
    int off0 = (w == 1) ? ws2[0] : 0;
    if (t < nb) bsums[t] = off0 + x - v;
}

__global__ void k_scan3(int* __restrict__ rp, const int* __restrict__ bsums,
                        int* __restrict__ fill, int n){
    int i = blockIdx.x*256 + threadIdx.x;
    if (i < n){
        int r = rp[i] + bsums[i >> 10];
        rp[i] = r;
        fill[i] = r;
    }
    if (i == 0) rp[n] = EE;
}

// place edges sorted by dst; pack (src<<4)|(dst&15) — dst&15 is the row
// within the owning wave's 16-row tile (tiles are 16-aligned).
__global__ void k_place(const int* __restrict__ src, const int* __restrict__ dst,
                        int* __restrict__ fill, int* __restrict__ spk){
    int e = blockIdx.x*256 + threadIdx.x;
    if (e < EE){
        int d = dst[e];
        int p = atomicAdd(&fill[d], 1);
        spk[p] = (src[e] << 4) | (d & 15);
    }
}

// ---------------- init: zero fill + graph rowptr + W pre-swizzle (merged) ----
__global__ void k_init(const int* __restrict__ batch, int* __restrict__ fill,
                       int* __restrict__ rp_g,
                       const float* __restrict__ W2_0, const float* __restrict__ W1s,
                       const float* __restrict__ W2s, short* __restrict__ Wp){
    int tid = blockIdx.x*256 + threadIdx.x;
    if (tid < NN){
        fill[tid] = 0;
        int b = batch[tid];
        if (tid == 0){
            for (int g = 0; g <= b; g++) rp_g[g] = 0;
        } else {
            int p = batch[tid-1];
            for (int g = p+1; g <= b; g++) rp_g[g] = tid;
        }
        if (tid == NN-1){
            for (int g = b+1; g <= GG; g++) rp_g[g] = NN;
        }
    }
    if (tid < 9*16384){
        int m = tid >> 14;
        int r = tid & 16383;
        int j = r & 7, l = (r >> 3) & 63, ctkc = r >> 9;
        int ct = ctkc & 7, kc = ctkc >> 3;
        int k = kc*32 + ((l >> 4) << 3) + j;
        int n = (ct << 4) + (l & 15);
        const float* W = (m == 0) ? W2_0
                       : (m <= 4) ? (W1s + (size_t)(m-1)*HH*HH)
                                  : (W2s + (size_t)(m-5)*HH*HH);
        float w = W[k*HH + n];
        short hi = f2bf(w);
        short lo = f2bf(w - bf2f(hi));
        short* base = Wp + (size_t)m*32768;
        base[r] = hi;
        base[16384 + r] = lo;
    }
}

// ---------------- layer 0 aggregation (in=3) ----------------
__global__ void k_agg3(const float* __restrict__ x, const int* __restrict__ rp,
                       const int* __restrict__ spk, float* __restrict__ y){
    int i = blockIdx.x*256 + threadIdx.x;
    if (i >= NN) return;
    float a0 = x[3*i], a1 = x[3*i+1], a2 = x[3*i+2];
    int b = rp[i], e = rp[i+1];
    for (int k = b; k < e; k++){
        int s = spk[k] >> 4;
        a0 += x[3*s]; a1 += x[3*s+1]; a2 += x[3*s+2];
    }
    y[3*i] = a0; y[3*i+1] = a1; y[3*i+2] = a2;
}

// ============ per-wave LDS layouts (no cross-wave sharing, NO barriers) ======

__device__ inline void wave_gemm(const short* __restrict__ sAh,
                                 const short* __restrict__ sAl,
                                 const short* __restrict__ Wp,
                                 int n, int q, f32x4* acc){
    const short* Wh = Wp;
    const short* Wl = Wp + 16384;
    const int l = (q << 4) | n;
#pragma unroll
    for (int ct = 0; ct < 8; ct++) acc[ct] = (f32x4){0.f,0.f,0.f,0.f};
#pragma unroll
    for (int kc = 0; kc < 4; kc++){
        int c = (q << 4) | (n & 8) | ((n & 7) ^ ((q & 1) << 2) ^ kc);
        int pos = kc*512 + c*8;
        bf16x8 ah = *(const bf16x8*)&sAh[pos];
        bf16x8 al = *(const bf16x8*)&sAl[pos];
        const short* ph = Wh + (size_t)(kc*8)*512 + l*8;
        const short* pl = Wl + (size_t)(kc*8)*512 + l*8;
#pragma unroll
        for (int ct = 0; ct < 8; ct++){
            bf16x8 bh = *(const bf16x8*)(ph + ct*512);
            bf16x8 bl = *(const bf16x8*)(pl + ct*512);
            acc[ct] = __builtin_amdgcn_mfma_f32_16x16x32_bf16(ah, bh, acc[ct], 0, 0, 0);
            acc[ct] = __builtin_amdgcn_mfma_f32_16x16x32_bf16(al, bh, acc[ct], 0, 0, 0);
            acc[ct] = __builtin_amdgcn_mfma_f32_16x16x32_bf16(ah, bl, acc[ct], 0, 0, 0);
        }
    }
}

// ---------------- layer 0 fused: mlp0 + GEMM(W2_0); fp16 output ----
__global__ __launch_bounds__(256, 4)
void k_layer0(const float* __restrict__ y0, const short* __restrict__ Wp,
              const float* __restrict__ W1, const float* __restrict__ b1,
              const float* __restrict__ g, const float* __restrict__ be,
              const float* __restrict__ m, const float* __restrict__ v,
              const float* __restrict__ b2, f16* __restrict__ out){
    __shared__ __align__(16) char smem[32768];
    const int t = threadIdx.x;
    const int w = t >> 6, l = t & 63;
    short* sAh = (short*)(smem + w*8192);
    short* sAl = (short*)(smem + w*8192 + 4096);
    const int R0 = blockIdx.x*64 + w*16;

    {
        int hw = l >> 5, ln = l & 31;
        int c4 = ln << 2;
        int kc1 = ln >> 3, q1 = (ln >> 1) & 3, j1 = (ln & 1) << 2;
        float Wc[3][4], Ac[4], Bc[4];
#pragma unroll
        for (int i = 0; i < 4; i++){
            int c = c4 + i;
            float rs = rsqrtf(v[c] + 1e-5f);
            float sc = g[c]*rs;
            Ac[i] = sc;
            Bc[i] = sc*(b1[c] - m[c]) + be[c];
            Wc[0][i] = W1[c]; Wc[1][i] = W1[HH + c]; Wc[2][i] = W1[2*HH + c];
        }
        float ya[8], yb[8], yc[8];
#pragma unroll
        for (int it = 0; it < 8; it++){
            int node = R0 + hw + (it << 1);
            ya[it] = y0[3*node]; yb[it] = y0[3*node+1]; yc[it] = y0[3*node+2];
        }
#pragma unroll
        for (int it = 0; it < 8; it++){
            int mm = hw + (it << 1);
            float xs[4];
#pragma unroll
            for (int i = 0; i < 4; i++){
                float raw = ya[it]*Wc[0][i] + yb[it]*Wc[1][i] + yc[it]*Wc[2][i];
                xs[i] = fmaxf(fmaf(raw, Ac[i], Bc[i]), 0.f);
            }
            int c = (q1 << 4) | (mm & 8) | ((mm & 7) ^ ((q1 & 1) << 2) ^ kc1);
            int pos = kc1*512 + c*8 + j1;
            unsigned hp[2], lp[2];
#pragma unroll
            for (int i = 0; i < 2; i++){
                unsigned u0 = __float_as_uint(xs[2*i]);
                unsigned u1 = __float_as_uint(xs[2*i+1]);
                float r0 = xs[2*i]   - __uint_as_float(u0 & 0xFFFF0000u);
                float r1 = xs[2*i+1] - __uint_as_float(u1 & 0xFFFF0000u);
                hp[i] = (u0 >> 16) | (u1 & 0xFFFF0000u);
                lp[i] = (__float_as_uint(r0) >> 16) | (__float_as_uint(r1) & 0xFFFF0000u);
            }
            *(uint2*)&sAh[pos] = make_uint2(hp[0], hp[1]);
            *(uint2*)&sAl[pos] = make_uint2(lp[0], lp[1]);
        }
    }
    __asm__ volatile("" ::: "memory");

    const int n = l & 15, q = l >> 4;
    f32x4 acc[8];
    wave_gemm(sAh, sAl, Wp, n, q, acc);
#pragma unroll
    for (int ct = 0; ct < 8; ct++){
        int j = (ct << 4) + n;
        float shv = b2[j];
#pragma unroll
        for (int r = 0; r < 4; r++){
            int row = R0 + q*4 + r;
            out[(size_t)row*HH + j] = (f16)fmaxf(acc[ct][r] + shv, 0.f);
        }
    }
}

// ================= full GIN layer: fp16 h, 32-edge-chunk gather, f32-LDS GEMMs
// 128-thread (2-wave) blocks: 16 KB LDS/block -> 10 blocks/CU (LDS-bound)
// -> 20 waves/CU occupancy cap, double the 256-thread version.
// LDS tile per wave: 16 rows x 128 f32 (8 KB), XOR-swizzled:
//   idx(row,k) = row*128 + (k ^ ((row&7)<<2))
__device__ __forceinline__ int sidx(int r, int k){
    return r*128 + (k ^ ((r & 7) << 2));
}

// GEMM with A read from f32 LDS tile, split to bf16 hi/lo on the fly.
__device__ __forceinline__ void wave_gemm_f32(const float* __restrict__ sF,
                                              const short* __restrict__ Wp,
                                              int l, f32x4* acc){
    const short* Wh = Wp;
    const short* Wl = Wp + 16384;
    const int rw = l & 15, q = l >> 4;
    const int v7 = (rw & 7) << 2;
    const int rbase = rw << 7;
#pragma unroll
    for (int ct = 0; ct < 8; ct++) acc[ct] = (f32x4){0.f,0.f,0.f,0.f};
#pragma unroll
    for (int kc = 0; kc < 4; kc++){
        int k0 = kc*32 + (q << 3);
        float4 fa = *(const float4*)&sF[rbase + ((k0    ) ^ v7)];
        float4 fb = *(const float4*)&sF[rbase + ((k0 + 4) ^ v7)];
        float xs[8] = {fa.x,fa.y,fa.z,fa.w,fb.x,fb.y,fb.z,fb.w};
        bf16x8 ah, al;
#pragma unroll
        for (int i = 0; i < 8; i++){
            unsigned u = __float_as_uint(xs[i]);
            ah[i] = (short)(u >> 16);
            float rv = xs[i] - __uint_as_float(u & 0xFFFF0000u);
            al[i] = (short)(__float_as_uint(rv) >> 16);
        }
        const short* ph = Wh + (size_t)(kc*8)*512 + l*8;
        const short* pl = Wl + (size_t)(kc*8)*512 + l*8;
#pragma unroll
        for (int ct = 0; ct < 8; ct++){
            bf16x8 bh = *(const bf16x8*)(ph + ct*512);
            bf16x8 bl = *(const bf16x8*)(pl + ct*512);
            acc[ct] = __builtin_amdgcn_mfma_f32_16x16x32_bf16(ah, bh, acc[ct], 0, 0, 0);
            acc[ct] = __builtin_amdgcn_mfma_f32_16x16x32_bf16(al, bh, acc[ct], 0, 0, 0);
            acc[ct] = __builtin_amdgcn_mfma_f32_16x16x32_bf16(ah, bl, acc[ct], 0, 0, 0);
        }
    }
}

__global__ __launch_bounds__(128, 5)
void k_layer(const f16* __restrict__ A, const int* __restrict__ rp,
             const int* __restrict__ spk,
             const short* __restrict__ Wp1, const short* __restrict__ Wp2,
             const float* __restrict__ b1, const float* __restrict__ g,
             const float* __restrict__ be, const float* __restrict__ m,
             const float* __restrict__ v, const float* __restrict__ b2,
             f16* __restrict__ out){
    __shared__ __align__(16) float smemf[4096];   // 16 KB, 8 KB per wave
    const int t = threadIdx.x;
    const int w = t >> 6, l = t & 63;
    float* sF = smemf + w*2048;
    const int r0w = blockIdx.x*32 + w*16;
    const unsigned* A2 = (const unsigned*)A;      // 64 dwords per row

    // ---- phase 1a: self rows -> LDS (swizzled), dwordx2 per lane ----
    {
        int half = l >> 5, lm = l & 31;
        int k0 = lm << 2;                          // float col base (4 per lane)
#pragma unroll
        for (int i = 0; i < 8; i++){
            int r = (i << 1) + half;
            uint2 u = *(const uint2*)&A2[(size_t)(r0w + r)*64 + (lm << 1)];
            float2 f0 = cvt2(u.x), f1 = cvt2(u.y);
            int base = r*128 + (k0 ^ ((r & 7) << 2));   // 4-aligned after xor
            *(float4*)&sF[base] = make_float4(f0.x, f0.y, f1.x, f1.y);
        }
    }

    // ---- phase 1b: flat edge walk, 32-edge chunks, idx 2-ahead, data 1-ahead
    {
        int rlo = r0w < NN ? r0w : NN;
        int rhi = (r0w + 16) < NN ? (r0w + 16) : NN;   // NN%16==0: no straddle
        int elo = __builtin_amdgcn_readfirstlane(rp[rlo]);
        int ehi = __builtin_amdgcn_readfirstlane(rp[rhi]);
        int nE  = ehi - elo;
        int nfull = nE >> 5;
        int remT  = nE & 31;
        int lm = l & 31;
        float acc0 = 0.f, acc1 = 0.f;
        int cur = -1;
        unsigned uA[32], uB[32];

        // idx chunks (lane-broadcast). spk padded by 128 ints -> over-read safe.
        int idxA = spk[elo + lm];
        int idxB = spk[elo + 32 + lm];

        // prologue: data for chunk 0 (only if it's a full chunk)
        if (nfull > 0){
#pragma unroll
            for (int j = 0; j < 32; j++){
                int sj = __builtin_amdgcn_readlane(idxA, j) >> 4;
                uA[j] = A2[(size_t)sj*64 + l];
            }
        }

        int e = elo;
        for (int c = 0; c < nfull; c++){
            int idxN = spk[e + 64 + lm];          // idx for chunk c+2 (padded)
            int remN = nE - (c + 1)*32;           // edges in next chunk
            if (remN >= 32){                      // next chunk full: no guards
#pragma unroll
                for (int j = 0; j < 32; j++){
                    int sj = __builtin_amdgcn_readlane(idxB, j) >> 4;
                    uB[j] = A2[(size_t)sj*64 + l];
                }
            } else {                              // next is the partial tail
#pragma unroll
                for (int j = 0; j < 32; j++){
                    if (j < remN){
                        int sj = __builtin_amdgcn_readlane(idxB, j) >> 4;
                        uB[j] = A2[(size_t)sj*64 + l];
                    }
                }
            }
            // process chunk c (no guards: full chunk)
#pragma unroll
            for (int j = 0; j < 32; j++){
                int si = __builtin_amdgcn_readlane(idxA, j);
                int lr = si & 15;
                if (lr != cur){                   // wave-uniform branch
                    if (cur >= 0){
                        int off = cur*128 + ((2*l) ^ ((cur & 7) << 2));
                        *(float2*)&sF[off] = make_float2(acc0, acc1);
                    }
                    cur = lr;
                    int off = lr*128 + ((2*l) ^ ((lr & 7) << 2));
                    float2 sv = *(const float2*)&sF[off];
                    acc0 = sv.x; acc1 = sv.y;
                }
                float2 fv = cvt2(uA[j]);
                acc0 += fv.x; acc1 += fv.y;
            }
            idxA = idxB; idxB = idxN;
#pragma unroll
            for (int j = 0; j < 32; j++) uA[j] = uB[j];
            e += 32;
        }
        // tail: remT edges now sit in uA (loaded by last main iter), unless
        // there was no main iter at all.
        if (nfull == 0 && remT > 0){
#pragma unroll
            for (int j = 0; j < 32; j++){
                if (j < remT){
                    int sj = __builtin_amdgcn_readlane(idxA, j) >> 4;
                    uA[j] = A2[(size_t)sj*64 + l];
                }
            }
        }
#pragma unroll
        for (int j = 0; j < 32; j++){
            if (j < remT){
                int si = __builtin_amdgcn_readlane(idxA, j);
                int lr = si & 15;
                if (lr != cur){
                    if (cur >= 0){
                        int off = cur*128 + ((2*l) ^ ((cur & 7) << 2));
                        *(float2*)&sF[off] = make_float2(acc0, acc1);
                    }
                    cur = lr;
                    int off = lr*128 + ((2*l) ^ ((lr & 7) << 2));
                    float2 sv = *(const float2*)&sF[off];
                    acc0 = sv.x; acc1 = sv.y;
                }
                float2 fv = cvt2(uA[j]);
                acc0 += fv.x; acc1 += fv.y;
            }
        }
        if (cur >= 0){
            int off = cur*128 + ((2*l) ^ ((cur & 7) << 2));
            *(float2*)&sF[off] = make_float2(acc0, acc1);
        }
    }
    __asm__ volatile("" ::: "memory");

    const int n = l & 15, q = l >> 4;

    // ---- phase 2: GEMM1 (A from f32 LDS); BN/ReLU epilogue -> back to LDS ----
    f32x4 acc[8];
    wave_gemm_f32(sF, Wp1, l, acc);
    __asm__ volatile("" ::: "memory");
#pragma unroll
    for (int ct = 0; ct < 8; ct++){
        int j = (ct << 4) + n;
        float rr = rsqrtf(v[j] + 1e-5f);
        float scv = g[j]*rr;
        float shv = be[j] + scv*(b1[j] - m[j]);
#pragma unroll
        for (int r = 0; r < 4; r++){
            int row = (q << 2) + r;
            float vv = fmaxf(fmaf(acc[ct][r], scv, shv), 0.f);
            sF[sidx(row, j)] = vv;
        }
    }
    __asm__ volatile("" ::: "memory");

    // ---- phase 3: GEMM2 + bias/ReLU -> global (fp16) ----
    wave_gemm_f32(sF, Wp2, l, acc);
#pragma unroll
    for (int ct = 0; ct < 8; ct++){
        int j = (ct << 4) + n;
        float shv = b2[j];
#pragma unroll
        for (int r = 0; r < 4; r++){
            int row = r0w + (q << 2) + r;
            out[(size_t)row*HH + j] = (f16)fmaxf(acc[ct][r] + shv, 0.f);
        }
    }
}

// ---------------- pooling + classifier: block per graph, no atomics ---------
__global__ void k_pool2(const f16* __restrict__ h, const float* __restrict__ Wc,
                        const float* __restrict__ bc, const int* __restrict__ rp_g,
                        float* __restrict__ out){
    __shared__ float ws[4];
    int g = blockIdx.x, t = threadIdx.x;
    const unsigned* h2 = (const unsigned*)h;      // 64 dwords per row
    long beg = (long)rp_g[g]*64, end = (long)rp_g[g+1]*64;
    float s = 0.f;
    for (long i = beg + t; i < end; i += 256){
        unsigned u = h2[i];
        int p = (int)(i & 63);
        float2 fv = cvt2(u);
        s += fv.x*Wc[2*p] + fv.y*Wc[2*p+1];
    }
    int lane = t & 63, w = t >> 6;
#pragma unroll
    for (int off = 32; off > 0; off >>= 1) s += __shfl_down(s, off);
    if (lane == 0) ws[w] = s;
    __syncthreads();
    if (t == 0) out[g] = bc[0] + ws[0] + ws[1] + ws[2] + ws[3];
}

extern "C" void kernel_launch(void* const* d_in, const int* in_sizes, int n_in,
                              void* d_out, int out_size, void* d_ws, size_t ws_size,
                              hipStream_t stream){
    const float* x     = (const float*)d_in[0];
    const int*   ei    = (const int*)d_in[1];
    const int*   batch = (const int*)d_in[2];
    const float* W1_0  = (const float*)d_in[3];
    const float* b1_0  = (const float*)d_in[4];
    const float* g_0   = (const float*)d_in[5];
    const float* be_0  = (const float*)d_in[6];
    const float* m_0   = (const float*)d_in[7];
    const float* v_0   = (const float*)d_in[8];
    const float* W2_0  = (const float*)d_in[9];
    const float* b2_0  = (const float*)d_in[10];
    const float* W1s   = (const float*)d_in[11];
    const float* b1s   = (const float*)d_in[12];
    const float* gs    = (const float*)d_in[13];
    const float* bes   = (const float*)d_in[14];
    const float* ms    = (const float*)d_in[15];
    const float* vs    = (const float*)d_in[16];
    const float* W2s   = (const float*)d_in[17];
    const float* b2s   = (const float*)d_in[18];
    const float* Wc    = (const float*)d_in[19];
    const float* bc    = (const float*)d_in[20];

    f16* H0 = (f16*)d_ws;                         // NPAD*HH halfs
    f16* H1 = H0 + (size_t)NPAD*HH;
    int* rp    = (int*)(H1 + (size_t)NPAD*HH);
    int* fill  = rp + (NN + 1);
    int* spk   = fill + NN;
    int* bsums = spk + EE + 128;                  // spk padded by 128 ints
    int* rp_g  = bsums + 128;
    size_t off = (size_t)((char*)(rp_g + (GG + 1)) - (char*)d_ws);
    off = (off + 15) & ~(size_t)15;
    short* Wp = (short*)((char*)d_ws + off);      // 9 x 32768 shorts (hi+lo)
    float* Y  = (float*)H1;                       // f32 agg3 output (aliases H1)

    const int* src = ei;
    const int* dst = ei + EE;

    // --- init (zero fill + rp_g bounds + weight pre-swizzle, one kernel) ---
    k_init<<<(9*16384+255)/256, 256, 0, stream>>>(batch, fill, rp_g,
                                                  W2_0, W1s, W2s, Wp);

    // --- CSR build ---
    k_hist<<<(EE+255)/256, 256, 0, stream>>>(dst, fill);
    k_scan1<<<98, 256, 0, stream>>>(fill, rp, bsums, NN);
    k_scan2<<<1, 128, 0, stream>>>(bsums, 98);
    k_scan3<<<(NN+255)/256, 256, 0, stream>>>(rp, bsums, fill, NN);
    k_place<<<(EE+255)/256, 256, 0, stream>>>(src, dst, fill, spk);

    // --- layer 0: agg3 (f32, into Y=H1 alias) -> fused mlp0+GEMM -> H0 fp16 ---
    k_agg3<<<(NN+255)/256, 256, 0, stream>>>(x, rp, spk, Y);
    k_layer0<<<NBLK2, 256, 0, stream>>>(Y, Wp, W1_0, b1_0, g_0, be_0, m_0, v_0,
                                        b2_0, H0);

    // --- layers 1..4: one fused barrier-free kernel per layer, 2-wave blocks --
    f16* cur = H0; f16* oth = H1;
    for (int l = 0; l < 4; l++){
        k_layer<<<NBLKL, 128, 0, stream>>>(cur, rp, spk,
                                           Wp + (size_t)(1+l)*32768,
                                           Wp + (size_t)(5+l)*32768,
                                           b1s + l*HH, gs + l*HH, bes + l*HH,
                                           ms + l*HH, vs + l*HH, b2s + l*HH,
                                           oth);
        f16* tmp = cur; cur = oth; oth = tmp;
    }

    // --- pooling + classifier (no atomics) ---
    k_pool2<<<GG, 256, 0, stream>>>(cur, Wc, bc, rp_g, (float*)d_out);
}

// Round 10
// 433.919 us; speedup vs baseline: 1.1279x; 1.0487x over previous
//
#include <hip/hip_runtime.h>

#define NN 100000
#define EE 600000
#define HH 128
#define GG 1000
#define NPAD 100096   // 1564 * 64
#define NBLK2 1564    // k_layer0: 64 rows/block
#define NBLKL 3128    // k_layer: 32 rows/block (2 waves x 16)

typedef __attribute__((ext_vector_type(8))) short bf16x8;
typedef __attribute__((ext_vector_type(4))) float f32x4;
typedef _Float16 f16;

__device__ inline short f2bf(float x){
    unsigned u = __float_as_uint(x);
    unsigned r = (u + 0x7FFFu + ((u >> 16) & 1u)) >> 16;
    return (short)r;
}
__device__ inline float bf2f(short h){
    unsigned u = ((unsigned)(unsigned short)h) << 16;
    return __uint_as_float(u);
}
__device__ inline float2 cvt2(unsigned u){
    f16 lo = ((const f16*)&u)[0];
    f16 hi = ((const f16*)&u)[1];
    return make_float2((float)lo, (float)hi);
}

// ---------------- CSR build ----------------
__global__ void k_hist(const int* __restrict__ dst, int* __restrict__ cnt){
    int e = blockIdx.x*256 + threadIdx.x;
    if (e < EE) atomicAdd(&cnt[dst[e]], 1);
}

__global__ void k_scan1(const int* __restrict__ cnt, int* __restrict__ excl,
                        int* __restrict__ bsums, int n){
    __shared__ int wsum[4];
    int t = threadIdx.x;
    int idx = blockIdx.x*1024 + t*4;
    int c[4];
#pragma unroll
    for (int i = 0; i < 4; i++) c[i] = (idx+i < n) ? cnt[idx+i] : 0;
    int s = c[0]+c[1]+c[2]+c[3];
    int lane = t & 63, w = t >> 6;
    int x = s;
#pragma unroll
    for (int off = 1; off < 64; off <<= 1){
        int y = __shfl_up(x, off);
        if (lane >= off) x += y;
    }
    if (lane == 63) wsum[w] = x;
    __syncthreads();
    int woff = 0;
    for (int i = 0; i < w; i++) woff += wsum[i];
    int run = woff + x - s;
#pragma unroll
    for (int i = 0; i < 4; i++){
        if (idx+i < n) excl[idx+i] = run;
        run += c[i];
    }
    if (t == 255) bsums[blockIdx.x] = woff + x;
}

__global__ void k_scan2(int* __restrict__ bsums, int nb){
    __shared__ int ws2[2];
    int t = threadIdx.x;
    int v = (t < nb) ? bsums[t] : 0;
    int lane = t & 63, w = t >> 6;
    int x = v;
#pragma unroll
    for (int off = 1; off < 64; off <<= 1){
        int y = __shfl_up(x, off);
        if (lane >= off) x += y;
    }
    if (lane == 63) ws2[w] = x;
    __syncthreads();
    int off0 = (w == 1) ? ws2[0] : 0;
    if (t < nb) bsums[t] = off0 + x - v;
}

__global__ void k_scan3(int* __restrict__ rp, const int* __restrict__ bsums,
                        int* __restrict__ fill, int n){
    int i = blockIdx.x*256 + threadIdx.x;
    if (i < n){
        int r = rp[i] + bsums[i >> 10];
        rp[i] = r;
        fill[i] = r;
    }
    if (i == 0) rp[n] = EE;
}

// place edges sorted by dst; pack (src<<4)|(dst&15) — dst&15 is the row
// within the owning wave's 16-row tile (tiles are 16-aligned).
__global__ void k_place(const int* __restrict__ src, const int* __restrict__ dst,
                        int* __restrict__ fill, int* __restrict__ spk){
    int e = blockIdx.x*256 + threadIdx.x;
    if (e < EE){
        int d = dst[e];
        int p = atomicAdd(&fill[d], 1);
        spk[p] = (src[e] << 4) | (d & 15);
    }
}

// ---------------- init: zero fill + graph rowptr + W pre-swizzle (merged) ----
__global__ void k_init(const int* __restrict__ batch, int* __restrict__ fill,
                       int* __restrict__ rp_g,
                       const float* __restrict__ W2_0, const float* __restrict__ W1s,
                       const float* __restrict__ W2s, short* __restrict__ Wp){
    int tid = blockIdx.x*256 + threadIdx.x;
    if (tid < NN){
        fill[tid] = 0;
        int b = batch[tid];
        if (tid == 0){
            for (int g = 0; g <= b; g++) rp_g[g] = 0;
        } else {
            int p = batch[tid-1];
            for (int g = p+1; g <= b; g++) rp_g[g] = tid;
        }
        if (tid == NN-1){
            for (int g = b+1; g <= GG; g++) rp_g[g] = NN;
        }
    }
    if (tid < 9*16384){
        int m = tid >> 14;
        int r = tid & 16383;
        int j = r & 7, l = (r >> 3) & 63, ctkc = r >> 9;
        int ct = ctkc & 7, kc = ctkc >> 3;
        int k = kc*32 + ((l >> 4) << 3) + j;
        int n = (ct << 4) + (l & 15);
        const float* W = (m == 0) ? W2_0
                       : (m <= 4) ? (W1s + (size_t)(m-1)*HH*HH)
                                  : (W2s + (size_t)(m-5)*HH*HH);
        float w = W[k*HH + n];
        short hi = f2bf(w);
        short lo = f2bf(w - bf2f(hi));
        short* base = Wp + (size_t)m*32768;
        base[r] = hi;
        base[16384 + r] = lo;
    }
}

// ---------------- layer 0 aggregation (in=3) ----------------
__global__ void k_agg3(const float* __restrict__ x, const int* __restrict__ rp,
                       const int* __restrict__ spk, float* __restrict__ y){
    int i = blockIdx.x*256 + threadIdx.x;
    if (i >= NN) return;
    float a0 = x[3*i], a1 = x[3*i+1], a2 = x[3*i+2];
    int b = rp[i], e = rp[i+1];
    for (int k = b; k < e; k++){
        int s = spk[k] >> 4;
        a0 += x[3*s]; a1 += x[3*s+1]; a2 += x[3*s+2];
    }
    y[3*i] = a0; y[3*i+1] = a1; y[3*i+2] = a2;
}

// ============ per-wave LDS layouts (no cross-wave sharing, NO barriers) ======

__device__ inline void wave_gemm(const short* __restrict__ sAh,
                                 const short* __restrict__ sAl,
                                 const short* __restrict__ Wp,
                                 int n, int q, f32x4* acc){
    const short* Wh = Wp;
    const short* Wl = Wp + 16384;
    const int l = (q << 4) | n;
#pragma unroll
    for (int ct = 0; ct < 8; ct++) acc[ct] = (f32x4){0.f,0.f,0.f,0.f};
#pragma unroll
    for (int kc = 0; kc < 4; kc++){
        int c = (q << 4) | (n & 8) | ((n & 7) ^ ((q & 1) << 2) ^ kc);
        int pos = kc*512 + c*8;
        bf16x8 ah = *(const bf16x8*)&sAh[pos];
        bf16x8 al = *(const bf16x8*)&sAl[pos];
        const short* ph = Wh + (size_t)(kc*8)*512 + l*8;
        const short* pl = Wl + (size_t)(kc*8)*512 + l*8;
#pragma unroll
        for (int ct = 0; ct < 8; ct++){
            bf16x8 bh = *(const bf16x8*)(ph + ct*512);
            bf16x8 bl = *(const bf16x8*)(pl + ct*512);
            acc[ct] = __builtin_amdgcn_mfma_f32_16x16x32_bf16(ah, bh, acc[ct], 0, 0, 0);
            acc[ct] = __builtin_amdgcn_mfma_f32_16x16x32_bf16(al, bh, acc[ct], 0, 0, 0);
            acc[ct] = __builtin_amdgcn_mfma_f32_16x16x32_bf16(ah, bl, acc[ct], 0, 0, 0);
        }
    }
}

// ---------------- layer 0 fused: mlp0 + GEMM(W2_0); fp16 output ----
__global__ __launch_bounds__(256, 4)
void k_layer0(const float* __restrict__ y0, const short* __restrict__ Wp,
              const float* __restrict__ W1, const float* __restrict__ b1,
              const float* __restrict__ g, const float* __restrict__ be,
              const float* __restrict__ m, const float* __restrict__ v,
              const float* __restrict__ b2, f16* __restrict__ out){
    __shared__ __align__(16) char smem[32768];
    const int t = threadIdx.x;
    const int w = t >> 6, l = t & 63;
    short* sAh = (short*)(smem + w*8192);
    short* sAl = (short*)(smem + w*8192 + 4096);
    const int R0 = blockIdx.x*64 + w*16;

    {
        int hw = l >> 5, ln = l & 31;
        int c4 = ln << 2;
        int kc1 = ln >> 3, q1 = (ln >> 1) & 3, j1 = (ln & 1) << 2;
        float Wc[3][4], Ac[4], Bc[4];
#pragma unroll
        for (int i = 0; i < 4; i++){
            int c = c4 + i;
            float rs = rsqrtf(v[c] + 1e-5f);
            float sc = g[c]*rs;
            Ac[i] = sc;
            Bc[i] = sc*(b1[c] - m[c]) + be[c];
            Wc[0][i] = W1[c]; Wc[1][i] = W1[HH + c]; Wc[2][i] = W1[2*HH + c];
        }
        float ya[8], yb[8], yc[8];
#pragma unroll
        for (int it = 0; it < 8; it++){
            int node = R0 + hw + (it << 1);
            ya[it] = y0[3*node]; yb[it] = y0[3*node+1]; yc[it] = y0[3*node+2];
        }
#pragma unroll
        for (int it = 0; it < 8; it++){
            int mm = hw + (it << 1);
            float xs[4];
#pragma unroll
            for (int i = 0; i < 4; i++){
                float raw = ya[it]*Wc[0][i] + yb[it]*Wc[1][i] + yc[it]*Wc[2][i];
                xs[i] = fmaxf(fmaf(raw, Ac[i], Bc[i]), 0.f);
            }
            int c = (q1 << 4) | (mm & 8) | ((mm & 7) ^ ((q1 & 1) << 2) ^ kc1);
            int pos = kc1*512 + c*8 + j1;
            unsigned hp[2], lp[2];
#pragma unroll
            for (int i = 0; i < 2; i++){
                unsigned u0 = __float_as_uint(xs[2*i]);
                unsigned u1 = __float_as_uint(xs[2*i+1]);
                float r0 = xs[2*i]   - __uint_as_float(u0 & 0xFFFF0000u);
                float r1 = xs[2*i+1] - __uint_as_float(u1 & 0xFFFF0000u);
                hp[i] = (u0 >> 16) | (u1 & 0xFFFF0000u);
                lp[i] = (__float_as_uint(r0) >> 16) | (__float_as_uint(r1) & 0xFFFF0000u);
            }
            *(uint2*)&sAh[pos] = make_uint2(hp[0], hp[1]);
            *(uint2*)&sAl[pos] = make_uint2(lp[0], lp[1]);
        }
    }
    __asm__ volatile("" ::: "memory");

    const int n = l & 15, q = l >> 4;
    f32x4 acc[8];
    wave_gemm(sAh, sAl, Wp, n, q, acc);
#pragma unroll
    for (int ct = 0; ct < 8; ct++){
        int j = (ct << 4) + n;
        float shv = b2[j];
#pragma unroll
        for (int r = 0; r < 4; r++){
            int row = R0 + q*4 + r;
            out[(size_t)row*HH + j] = (f16)fmaxf(acc[ct][r] + shv, 0.f);
        }
    }
}

// ================= full GIN layer: fp16 h, ping-pong gather, f32-LDS GEMMs ===
// 128-thread (2-wave) blocks, 16 KB LDS. Gather is a copy-free unroll-2
// ping-pong: even chunks in uA, odd in uB — buffers alternate by ROLE so the
// compiler can keep both live (no copy site to sink loads to).
// LDS tile per wave: 16 rows x 128 f32 (8 KB), XOR-swizzled:
//   idx(row,k) = row*128 + (k ^ ((row&7)<<2))
__device__ __forceinline__ int sidx(int r, int k){
    return r*128 + (k ^ ((r & 7) << 2));
}

// GEMM with A read from f32 LDS tile, split to bf16 hi/lo on the fly.
__device__ __forceinline__ void wave_gemm_f32(const float* __restrict__ sF,
                                              const short* __restrict__ Wp,
                                              int l, f32x4* acc){
    const short* Wh = Wp;
    const short* Wl = Wp + 16384;
    const int rw = l & 15, q = l >> 4;
    const int v7 = (rw & 7) << 2;
    const int rbase = rw << 7;
#pragma unroll
    for (int ct = 0; ct < 8; ct++) acc[ct] = (f32x4){0.f,0.f,0.f,0.f};
#pragma unroll
    for (int kc = 0; kc < 4; kc++){
        int k0 = kc*32 + (q << 3);
        float4 fa = *(const float4*)&sF[rbase + ((k0    ) ^ v7)];
        float4 fb = *(const float4*)&sF[rbase + ((k0 + 4) ^ v7)];
        float xs[8] = {fa.x,fa.y,fa.z,fa.w,fb.x,fb.y,fb.z,fb.w};
        bf16x8 ah, al;
#pragma unroll
        for (int i = 0; i < 8; i++){
            unsigned u = __float_as_uint(xs[i]);
            ah[i] = (short)(u >> 16);
            float rv = xs[i] - __uint_as_float(u & 0xFFFF0000u);
            al[i] = (short)(__float_as_uint(rv) >> 16);
        }
        const short* ph = Wh + (size_t)(kc*8)*512 + l*8;
        const short* pl = Wl + (size_t)(kc*8)*512 + l*8;
#pragma unroll
        for (int ct = 0; ct < 8; ct++){
            bf16x8 bh = *(const bf16x8*)(ph + ct*512);
            bf16x8 bl = *(const bf16x8*)(pl + ct*512);
            acc[ct] = __builtin_amdgcn_mfma_f32_16x16x32_bf16(ah, bh, acc[ct], 0, 0, 0);
            acc[ct] = __builtin_amdgcn_mfma_f32_16x16x32_bf16(al, bh, acc[ct], 0, 0, 0);
            acc[ct] = __builtin_amdgcn_mfma_f32_16x16x32_bf16(ah, bl, acc[ct], 0, 0, 0);
        }
    }
}

// per-edge accumulate with wave-uniform row-switch bookkeeping
#define PROC_EDGE(uval, sival) do { \
    int lr_ = (sival) & 15; \
    if (lr_ != cur){ \
        if (cur >= 0){ \
            int off_ = cur*128 + ((2*l) ^ ((cur & 7) << 2)); \
            *(float2*)&sF[off_] = make_float2(acc0, acc1); \
        } \
        cur = lr_; \
        int off_ = lr_*128 + ((2*l) ^ ((lr_ & 7) << 2)); \
        float2 sv_ = *(const float2*)&sF[off_]; \
        acc0 = sv_.x; acc1 = sv_.y; \
    } \
    float2 fv_ = cvt2(uval); \
    acc0 += fv_.x; acc1 += fv_.y; \
} while (0)

#define ISSUE_FULL(U, J) do { \
    _Pragma("unroll") \
    for (int j_ = 0; j_ < 32; j_++){ \
        int sj_ = __builtin_amdgcn_readlane((J), j_) >> 4; \
        U[j_] = A2[(size_t)sj_*64 + l]; \
    } \
} while (0)

#define ISSUE_PART(U, J) do { \
    _Pragma("unroll") \
    for (int j_ = 0; j_ < 32; j_++){ \
        if (j_ < remT){ \
            int sj_ = __builtin_amdgcn_readlane((J), j_) >> 4; \
            U[j_] = A2[(size_t)sj_*64 + l]; \
        } \
    } \
} while (0)

#define PROC_FULL(U, J) do { \
    _Pragma("unroll") \
    for (int j_ = 0; j_ < 32; j_++){ \
        int si_ = __builtin_amdgcn_readlane((J), j_); \
        PROC_EDGE(U[j_], si_); \
    } \
} while (0)

#define PROC_PART(U, J) do { \
    _Pragma("unroll") \
    for (int j_ = 0; j_ < 32; j_++){ \
        if (j_ < remT){ \
            int si_ = __builtin_amdgcn_readlane((J), j_); \
            PROC_EDGE(U[j_], si_); \
        } \
    } \
} while (0)

__global__ __launch_bounds__(128, 4)
void k_layer(const f16* __restrict__ A, const int* __restrict__ rp,
             const int* __restrict__ spk,
             const short* __restrict__ Wp1, const short* __restrict__ Wp2,
             const float* __restrict__ b1, const float* __restrict__ g,
             const float* __restrict__ be, const float* __restrict__ m,
             const float* __restrict__ v, const float* __restrict__ b2,
             f16* __restrict__ out){
    __shared__ __align__(16) float smemf[4096];   // 16 KB, 8 KB per wave
    const int t = threadIdx.x;
    const int w = t >> 6, l = t & 63;
    float* sF = smemf + w*2048;
    const int r0w = blockIdx.x*32 + w*16;
    const unsigned* A2 = (const unsigned*)A;      // 64 dwords per row

    // ---- phase 1a: self rows -> LDS (swizzled), dwordx2 per lane ----
    {
        int half = l >> 5, lm = l & 31;
        int k0 = lm << 2;                          // float col base (4 per lane)
#pragma unroll
        for (int i = 0; i < 8; i++){
            int r = (i << 1) + half;
            uint2 u = *(const uint2*)&A2[(size_t)(r0w + r)*64 + (lm << 1)];
            float2 f0 = cvt2(u.x), f1 = cvt2(u.y);
            int base = r*128 + (k0 ^ ((r & 7) << 2));   // 4-aligned after xor
            *(float4*)&sF[base] = make_float4(f0.x, f0.y, f1.x, f1.y);
        }
    }

    // ---- phase 1b: copy-free unroll-2 ping-pong gather ----
    // Iteration: issue uB(c+1) | proc uA(c) | issue uA(c+2 or tail) |
    // proc uB(c+1); only scalar idx regs rotate. No data-array copies.
    {
        int rlo = r0w < NN ? r0w : NN;
        int rhi = (r0w + 16) < NN ? (r0w + 16) : NN;   // NN%16==0: no straddle
        int elo = __builtin_amdgcn_readfirstlane(rp[rlo]);
        int ehi = __builtin_amdgcn_readfirstlane(rp[rhi]);
        int nE  = ehi - elo;
        int nfull = nE >> 5;
        int remT  = nE & 31;
        int lm = l & 31;
        float acc0 = 0.f, acc1 = 0.f;
        int cur = -1;
        unsigned uA[32], uB[32];

        // idx chunks (lane-broadcast). spk padded by 128 ints; max over-read
        // offset is elo + (nfull+2)*32 + 31 <= ehi + 95 <= EE + 95: safe.
        int idxA = spk[elo + lm];
        int idxB = spk[elo + 32 + lm];
        int idxC = spk[elo + 64 + lm];

        if (nfull > 0){
            ISSUE_FULL(uA, idxA);           // chunk 0
        } else if (remT > 0){
            ISSUE_PART(uA, idxA);           // lone tail
        }

        int c = 0;
        while (c + 2 <= nfull){
            ISSUE_FULL(uB, idxB);                      // chunk c+1 (full)
            int idxD = spk[elo + (c+3)*32 + lm];
            int idxE = spk[elo + (c+4)*32 + lm];
            PROC_FULL(uA, idxA);                       // chunk c
            if (c + 2 < nfull){
                ISSUE_FULL(uA, idxC);                  // chunk c+2 (full)
            } else if (remT > 0){
                ISSUE_PART(uA, idxC);                  // tail (chunk nfull)
            }
            PROC_FULL(uB, idxB);                       // chunk c+1
            idxA = idxC; idxB = idxD; idxC = idxE;
            c += 2;
        }
        if (nfull - c == 1){
            // uA holds chunk c (prologue or prior iter); tail idx = idxB
            if (remT > 0) ISSUE_PART(uB, idxB);
            PROC_FULL(uA, idxA);
            if (remT > 0) PROC_PART(uB, idxB);
        } else {
            // nfull even (incl. 0): tail (if any) sits in uA, idx = idxA
            if (remT > 0) PROC_PART(uA, idxA);
        }
        if (cur >= 0){
            int off = cur*128 + ((2*l) ^ ((cur & 7) << 2));
            *(float2*)&sF[off] = make_float2(acc0, acc1);
        }
    }
    __asm__ volatile("" ::: "memory");

    const int n = l & 15, q = l >> 4;

    // ---- phase 2: GEMM1 (A from f32 LDS); BN/ReLU epilogue -> back to LDS ----
    f32x4 acc[8];
    wave_gemm_f32(sF, Wp1, l, acc);
    __asm__ volatile("" ::: "memory");
#pragma unroll
    for (int ct = 0; ct < 8; ct++){
        int j = (ct << 4) + n;
        float rr = rsqrtf(v[j] + 1e-5f);
        float scv = g[j]*rr;
        float shv = be[j] + scv*(b1[j] - m[j]);
#pragma unroll
        for (int r = 0; r < 4; r++){
            int row = (q << 2) + r;
            float vv = fmaxf(fmaf(acc[ct][r], scv, shv), 0.f);
            sF[sidx(row, j)] = vv;
        }
    }
    __asm__ volatile("" ::: "memory");

    // ---- phase 3: GEMM2 + bias/ReLU -> global (fp16) ----
    wave_gemm_f32(sF, Wp2, l, acc);
#pragma unroll
    for (int ct = 0; ct < 8; ct++){
        int j = (ct << 4) + n;
        float shv = b2[j];
#pragma unroll
        for (int r = 0; r < 4; r++){
            int row = r0w + (q << 2) + r;
            out[(size_t)row*HH + j] = (f16)fmaxf(acc[ct][r] + shv, 0.f);
        }
    }
}

// ---------------- pooling + classifier: block per graph, no atomics ---------
__global__ void k_pool2(const f16* __restrict__ h, const float* __restrict__ Wc,
                        const float* __restrict__ bc, const int* __restrict__ rp_g,
                        float* __restrict__ out){
    __shared__ float ws[4];
    int g = blockIdx.x, t = threadIdx.x;
    const unsigned* h2 = (const unsigned*)h;      // 64 dwords per row
    long beg = (long)rp_g[g]*64, end = (long)rp_g[g+1]*64;
    float s = 0.f;
    for (long i = beg + t; i < end; i += 256){
        unsigned u = h2[i];
        int p = (int)(i & 63);
        float2 fv = cvt2(u);
        s += fv.x*Wc[2*p] + fv.y*Wc[2*p+1];
    }
    int lane = t & 63, w = t >> 6;
#pragma unroll
    for (int off = 32; off > 0; off >>= 1) s += __shfl_down(s, off);
    if (lane == 0) ws[w] = s;
    __syncthreads();
    if (t == 0) out[g] = bc[0] + ws[0] + ws[1] + ws[2] + ws[3];
}

extern "C" void kernel_launch(void* const* d_in, const int* in_sizes, int n_in,
                              void* d_out, int out_size, void* d_ws, size_t ws_size,
                              hipStream_t stream){
    const float* x     = (const float*)d_in[0];
    const int*   ei    = (const int*)d_in[1];
    const int*   batch = (const int*)d_in[2];
    const float* W1_0  = (const float*)d_in[3];
    const float* b1_0  = (const float*)d_in[4];
    const float* g_0   = (const float*)d_in[5];
    const float* be_0  = (const float*)d_in[6];
    const float* m_0   = (const float*)d_in[7];
    const float* v_0   = (const float*)d_in[8];
    const float* W2_0  = (const float*)d_in[9];
    const float* b2_0  = (const float*)d_in[10];
    const float* W1s   = (const float*)d_in[11];
    const float* b1s   = (const float*)d_in[12];
    const float* gs    = (const float*)d_in[13];
    const float* bes   = (const float*)d_in[14];
    const float* ms    = (const float*)d_in[15];
    const float* vs    = (const float*)d_in[16];
    const float* W2s   = (const float*)d_in[17];
    const float* b2s   = (const float*)d_in[18];
    const float* Wc    = (const float*)d_in[19];
    const float* bc    = (const float*)d_in[20];

    f16* H0 = (f16*)d_ws;                         // NPAD*HH halfs
    f16* H1 = H0 + (size_t)NPAD*HH;
    int* rp    = (int*)(H1 + (size_t)NPAD*HH);
    int* fill  = rp + (NN + 1);
    int* spk   = fill + NN;
    int* bsums = spk + EE + 128;                  // spk padded by 128 ints
    int* rp_g  = bsums + 128;
    size_t off = (size_t)((char*)(rp_g + (GG + 1)) - (char*)d_ws);
    off = (off + 15) & ~(size_t)15;
    short* Wp = (short*)((char*)d_ws + off);      // 9 x 32768 shorts (hi+lo)
    float* Y  = (float*)H1;                       // f32 agg3 output (aliases H1)

    const int* src = ei;
    const int* dst = ei + EE;

    // --- init (zero fill + rp_g bounds + weight pre-swizzle, one kernel) ---
    k_init<<<(9*16384+255)/256, 256, 0, stream>>>(batch, fill, rp_g,
                                                  W2_0, W1s, W2s, Wp);

    // --- CSR build ---
    k_hist<<<(EE+255)/256, 256, 0, stream>>>(dst, fill);
    k_scan1<<<98, 256, 0, stream>>>(fill, rp, bsums, NN);
    k_scan2<<<1, 128, 0, stream>>>(bsums, 98);
    k_scan3<<<(NN+255)/256, 256, 0, stream>>>(rp, bsums, fill, NN);
    k_place<<<(EE+255)/256, 256, 0, stream>>>(src, dst, fill, spk);

    // --- layer 0: agg3 (f32, into Y=H1 alias) -> fused mlp0+GEMM -> H0 fp16 ---
    k_agg3<<<(NN+255)/256, 256, 0, stream>>>(x, rp, spk, Y);
    k_layer0<<<NBLK2, 256, 0, stream>>>(Y, Wp, W1_0, b1_0, g_0, be_0, m_0, v_0,
                                        b2_0, H0);

    // --- layers 1..4: one fused barrier-free kernel per layer, 2-wave blocks --
    f16* cur = H0; f16* oth = H1;
    for (int l = 0; l < 4; l++){
        k_layer<<<NBLKL, 128, 0, stream>>>(cur, rp, spk,
                                           Wp + (size_t)(1+l)*32768,
                                           Wp + (size_t)(5+l)*32768,
                                           b1s + l*HH, gs + l*HH, bes + l*HH,
                                           ms + l*HH, vs + l*HH, b2s + l*HH,
                                           oth);
        f16* tmp = cur; cur = oth; oth = tmp;
    }

    // --- pooling + classifier (no atomics) ---
    k_pool2<<<GG, 256, 0, stream>>>(cur, Wc, bc, rp_g, (float*)d_out);
}